// Round 11
// baseline (924.354 us; speedup 1.0000x reference)
//
#include <hip/hip_runtime.h>
#include <stdint.h>

// y[m,o] = sum_k x[m,k]*(W8[o,k]-zero[o])*scale[o] + bias[o], M=8192 N=11008 K=4096.
// x ~= xs_m*(128*h + l) (h,l int8); G = xs_m*(128*Gh + Gl) via two i8 MFMA GEMMs
// sharing B-frags; y = scale*G - scale*zero*rowsum + bias.
// R11: hybrid operand routing. A (h/l) staged in LDS (XOR swizzle, ring-2);
// B (W) read DIRECT global->reg from fragment-major layout (R7's, validated):
// one coalesced 1024B dwordx4 per frag, L2/L3-served (B tile shared by 64
// bm-blocks). LDS work/tile drops 2800->1790 cyc < MFMA 2610 -> MFMA-bound.
// B regs double-buffered; A-staging completion via hand-counted vmcnt(20)
// (issue order pinned by sched_barrier); last iteration peeled (vmcnt(8)).

#define M_DIM 8192
#define N_DIM 11008
#define K_DIM 4096
#define NT    (K_DIM / 128)   // 32 K-tiles
#define BUFB  32768           // per LDS buffer: Ah 16K | Al 16K

typedef __attribute__((ext_vector_type(4))) int i32x4;

// ---------------- prep kernels ----------------

// W int32 (int8-valued) [N][K] -> fragment-major Wq[q][c][r][16]:
// q = o>>4, r = o&15, c = k>>4. grid = N/16 = 688, block 256. (validated in R7)
__global__ __launch_bounds__(256) void convert_w_kernel(
    const int* __restrict__ w, int8_t* __restrict__ Wq) {
  const int q = blockIdx.x;
  const int r = threadIdx.x & 15;
  const int cg = threadIdx.x >> 4;          // 0..15, handles chunks cg*16..+15
  const int o = q * 16 + r;
  const int4* src = (const int4*)(w + (size_t)o * K_DIM + cg * 256);
  int8_t* dst = Wq + (size_t)q * 65536 + (size_t)(cg * 16) * 256 + r * 16;
  #pragma unroll 4
  for (int jc = 0; jc < 16; ++jc) {
    int4 o4;
    int4 v0 = src[jc * 4 + 0], v1 = src[jc * 4 + 1];
    int4 v2 = src[jc * 4 + 2], v3 = src[jc * 4 + 3];
    o4.x = (v0.x & 255) | ((v0.y & 255) << 8) | ((v0.z & 255) << 16) | ((v0.w & 255) << 24);
    o4.y = (v1.x & 255) | ((v1.y & 255) << 8) | ((v1.z & 255) << 16) | ((v1.w & 255) << 24);
    o4.z = (v2.x & 255) | ((v2.y & 255) << 8) | ((v2.z & 255) << 16) | ((v2.w & 255) << 24);
    o4.w = (v3.x & 255) | ((v3.y & 255) << 8) | ((v3.z & 255) << 16) | ((v3.w & 255) << 24);
    *(int4*)(dst + jc * 256) = o4;
  }
}

__global__ __launch_bounds__(256) void quantx_kernel(
    const float* __restrict__ x, int8_t* __restrict__ h8, int8_t* __restrict__ l8,
    float* __restrict__ xs, float* __restrict__ rsum) {
  const int row = blockIdx.x;
  const int t = threadIdx.x;
  const float4* px = (const float4*)(x + (size_t)row * K_DIM);
  float4 v[4];
  float mx = 0.f, sm = 0.f;
  #pragma unroll
  for (int i = 0; i < 4; ++i) {
    v[i] = px[i * 256 + t];
    mx = fmaxf(mx, fmaxf(fmaxf(fabsf(v[i].x), fabsf(v[i].y)),
                         fmaxf(fabsf(v[i].z), fabsf(v[i].w))));
    sm += v[i].x + v[i].y + v[i].z + v[i].w;
  }
  #pragma unroll
  for (int off = 32; off > 0; off >>= 1) {
    mx = fmaxf(mx, __shfl_down(mx, off));
    sm += __shfl_down(sm, off);
  }
  __shared__ float rmx[4], rsm[4];
  const int wv = t >> 6, ln = t & 63;
  if (ln == 0) { rmx[wv] = mx; rsm[wv] = sm; }
  __syncthreads();
  const float rowmax = fmaxf(fmaxf(rmx[0], rmx[1]), fmaxf(rmx[2], rmx[3]));
  if (t == 0) {
    xs[row] = rowmax > 0.f ? rowmax / 16256.f : 0.f;
    rsum[row] = rsm[0] + rsm[1] + rsm[2] + rsm[3];
  }
  const float inv = rowmax > 0.f ? 16256.f / rowmax : 0.f;
  int* hp = (int*)(h8 + (size_t)row * K_DIM);
  int* lp = (int*)(l8 + (size_t)row * K_DIM);
  #pragma unroll
  for (int i = 0; i < 4; ++i) {
    int q0 = (int)rintf(v[i].x * inv);
    int q1 = (int)rintf(v[i].y * inv);
    int q2 = (int)rintf(v[i].z * inv);
    int q3 = (int)rintf(v[i].w * inv);
    int h0 = (q0 + 64) >> 7, h1 = (q1 + 64) >> 7, h2 = (q2 + 64) >> 7, h3 = (q3 + 64) >> 7;
    int l0 = q0 - (h0 << 7), l1 = q1 - (h1 << 7), l2 = q2 - (h2 << 7), l3 = q3 - (h3 << 7);
    hp[i * 256 + t] = (h0 & 255) | ((h1 & 255) << 8) | ((h2 & 255) << 16) | ((h3 & 255) << 24);
    lp[i * 256 + t] = (l0 & 255) | ((l1 & 255) << 8) | ((l2 & 255) << 16) | ((l3 & 255) << 24);
  }
}

// ---------------- main GEMM ----------------

__device__ __forceinline__ void stage_A(
    const int8_t* __restrict__ Ah, const int8_t* __restrict__ Al,
    size_t a_base, int ks, int srow, int scol, int wave, int8_t* buf) {
  #pragma unroll
  for (int r = 0; r < 2; ++r) {
    const int8_t* g = Ah + a_base + (size_t)(r * 64 + srow) * K_DIM + ks + scol;
    __builtin_amdgcn_global_load_lds((const __attribute__((address_space(1))) void*)g,
        (__attribute__((address_space(3))) void*)(buf + r * 8192 + wave * 1024), 16, 0, 0);
  }
  #pragma unroll
  for (int r = 0; r < 2; ++r) {
    const int8_t* g = Al + a_base + (size_t)(r * 64 + srow) * K_DIM + ks + scol;
    __builtin_amdgcn_global_load_lds((const __attribute__((address_space(1))) void*)g,
        (__attribute__((address_space(3))) void*)(buf + 16384 + r * 8192 + wave * 1024), 16, 0, 0);
  }
}

__global__ __launch_bounds__(512, 2) void qgemm_kernel(
    const int8_t* __restrict__ Ah, const int8_t* __restrict__ Al,
    const int8_t* __restrict__ Wq, const float* __restrict__ xs,
    const float* __restrict__ rowsum, const float* __restrict__ scale,
    const float* __restrict__ zero, const float* __restrict__ bias,
    float* __restrict__ out) {
  extern __shared__ int8_t smem[];  // 2 x 32KB (A only)

  const int tid = threadIdx.x;
  const int wave = tid >> 6;
  const int lane = tid & 63;

  // XCD-chunked + grouped mapping: nwg=2752=8*344
  const int bid = blockIdx.x;
  const int wg = (bid & 7) * 344 + (bid >> 3);
  const int group = wg / 344;
  const int rem = wg % 344;
  const int bm = group * 8 + (rem & 7);  // 0..63 (M/128)
  const int bn = rem >> 3;               // 0..42 (N/256)

  const int wr = wave >> 2;  // 0..1: 64-row half of 128
  const int wc = wave & 3;   // 0..3: 64-col quarter of 256

  i32x4 acch[4][4], accl[4][4];
  #pragma unroll
  for (int i = 0; i < 4; ++i)
    #pragma unroll
    for (int j = 0; j < 4; ++j) {
      acch[i][j] = (i32x4){0, 0, 0, 0};
      accl[i][j] = (i32x4){0, 0, 0, 0};
    }

  // A staging (128B rows): thread owns phys slot (tid&7) of row (tid>>3);
  // load global slot (tid&7)^(row&7) so phys = logical ^ (row&7).
  const int srow = tid >> 3;                               // 0..63
  const int scol = (((tid & 7) ^ ((tid >> 3) & 7)) << 4);  // byte offset in row
  const size_t a_base = (size_t)(bm * 128) * K_DIM;

  // A fragment reads: logical slot = g (+4 for kk=64); row&7 == fr&7.
  const int fr = lane & 15;
  const int g = lane >> 4;
  const int sw = fr & 7;
  const int sc0 = ((g ^ sw) << 4);
  const int sc1 = (((g + 4) ^ sw) << 4);
  int arow[4];
  #pragma unroll
  for (int i = 0; i < 4; ++i) arow[i] = (wr * 64 + i * 16 + fr) * 128;

  // B fragment-major addressing: frag (ni, tile t, half hf) at
  // Wq + (bn*16 + wc*4 + ni)*65536 + t*2048 + hf*1024 + g*256 + fr*16
  const uint32_t laneoff = (uint32_t)(g * 256 + fr * 16);
  const int8_t* pb[4];
  #pragma unroll
  for (int ni = 0; ni < 4; ++ni)
    pb[ni] = Wq + (size_t)((uint32_t)(bn * 16 + wc * 4 + ni) * 65536u + laneoff);

#define LOADB(tt, bf) do {                                               \
    _Pragma("unroll")                                                    \
    for (int ni = 0; ni < 4; ++ni) {                                     \
      bf[ni][0] = *(const i32x4*)(pb[ni] + (uint32_t)(tt) * 2048u);      \
      bf[ni][1] = *(const i32x4*)(pb[ni] + (uint32_t)(tt) * 2048u + 1024u); \
    }                                                                    \
  } while (0)

#define RDA(sc, pAh, pAl, af) do {                                       \
    _Pragma("unroll")                                                    \
    for (int mi = 0; mi < 4; ++mi) {                                     \
      af[mi][0] = *(const i32x4*)((pAh) + arow[mi] + (sc));              \
      af[mi][1] = *(const i32x4*)((pAl) + arow[mi] + (sc));              \
    }                                                                    \
  } while (0)

#define MMH(af, bf, hf) do {                                             \
    __builtin_amdgcn_s_setprio(1);                                       \
    _Pragma("unroll")                                                    \
    for (int mi = 0; mi < 4; ++mi)                                       \
      _Pragma("unroll")                                                  \
      for (int ni = 0; ni < 4; ++ni) {                                   \
        acch[mi][ni] = __builtin_amdgcn_mfma_i32_16x16x64_i8(af[mi][0], bf[ni][hf], acch[mi][ni], 0, 0, 0); \
        accl[mi][ni] = __builtin_amdgcn_mfma_i32_16x16x64_i8(af[mi][1], bf[ni][hf], accl[mi][ni], 0, 0, 0); \
      }                                                                  \
    __builtin_amdgcn_s_setprio(0);                                       \
  } while (0)

  i32x4 bcur[4][2], bnxt[4][2], af[4][2];

  // prologue: stage A(0), load B(0)
  stage_A(Ah, Al, a_base, 0, srow, scol, wave, smem);
  __builtin_amdgcn_sched_barrier(0);
  LOADB(0, bcur);
  __builtin_amdgcn_sched_barrier(0);

  #pragma unroll 1
  for (int t = 0; t < NT - 1; ++t) {
    const int8_t* buf = smem + (t & 1) * BUFB;
    int8_t* nxt = smem + ((t + 1) & 1) * BUFB;

    // issue next tile's A staging (4) and B loads (8); pin issue order
    stage_A(Ah, Al, a_base, (t + 1) * 128, srow, scol, wave, nxt);
    __builtin_amdgcn_sched_barrier(0);
    LOADB(t + 1, bnxt);
    __builtin_amdgcn_sched_barrier(0);

    // wait A(t) staging complete: 20 VMEM issued after its last load
    // (B(t) 8 + A(t+1) 4 + B(t+1) 8); pinned by sched_barriers above.
    asm volatile("s_waitcnt vmcnt(20)" ::: "memory");
    __builtin_amdgcn_s_barrier();

    RDA(sc0, buf, buf + 16384, af);
    MMH(af, bcur, 0);
    RDA(sc1, buf, buf + 16384, af);
    MMH(af, bcur, 1);

    __builtin_amdgcn_s_barrier();  // all waves done reading buf -> reusable

    #pragma unroll
    for (int ni = 0; ni < 4; ++ni) {
      bcur[ni][0] = bnxt[ni][0];
      bcur[ni][1] = bnxt[ni][1];
    }
  }

  // peeled last tile: only B(NT-1) 8 issued after A(NT-1)'s last stage load
  {
    const int8_t* buf = smem + ((NT - 1) & 1) * BUFB;
    asm volatile("s_waitcnt vmcnt(8)" ::: "memory");
    __builtin_amdgcn_s_barrier();
    RDA(sc0, buf, buf + 16384, af);
    MMH(af, bcur, 0);
    RDA(sc1, buf, buf + 16384, af);
    MMH(af, bcur, 1);
  }

#undef LOADB
#undef RDA
#undef MMH

  // epilogue: G = xs_m*(128*Gh + Gl); y = scale*G - scale*zero*rowsum + bias
  // C/D 16x16: col = lane&15, row = (lane>>4)*4 + j
  const int row0 = bm * 128 + wr * 64;
  const int col0 = bn * 256 + wc * 64;
  float s_[4], sz_[4], b_[4];
  #pragma unroll
  for (int ni = 0; ni < 4; ++ni) {
    const int n = col0 + ni * 16 + fr;
    const float s = scale[n];
    s_[ni] = s;
    sz_[ni] = s * zero[n];
    b_[ni] = bias[n];
  }
  #pragma unroll
  for (int mi = 0; mi < 4; ++mi) {
    #pragma unroll
    for (int j = 0; j < 4; ++j) {
      const int m = row0 + mi * 16 + g * 4 + j;
      const float xsm = xs[m];
      const float rs = rowsum[m];
      float* po = out + (size_t)m * N_DIM + col0;
      #pragma unroll
      for (int ni = 0; ni < 4; ++ni) {
        const float G = xsm * (128.f * (float)acch[mi][ni][j] + (float)accl[mi][ni][j]);
        po[ni * 16 + fr] = s_[ni] * G - sz_[ni] * rs + b_[ni];
      }
    }
  }
}

// ---------------- fallback (only if workspace too small) ----------------

__global__ void fallback_kernel(const float* __restrict__ x, const int* __restrict__ w,
                                const float* __restrict__ scale, const float* __restrict__ zero,
                                const float* __restrict__ bias, float* __restrict__ out) {
  const int n = blockIdx.x * 16 + (threadIdx.x & 15);
  const int m = blockIdx.y * 16 + (threadIdx.x >> 4);
  const float z = zero[n];
  const float* xr = x + (size_t)m * K_DIM;
  const int* wr = w + (size_t)n * K_DIM;
  float acc = 0.f;
  for (int k = 0; k < K_DIM; ++k) acc += xr[k] * ((float)wr[k] - z);
  out[(size_t)m * N_DIM + n] = scale[n] * acc + bias[n];
}

// ---------------- launch ----------------

extern "C" void kernel_launch(void* const* d_in, const int* in_sizes, int n_in,
                              void* d_out, int out_size, void* d_ws, size_t ws_size,
                              hipStream_t stream) {
  const float* x     = (const float*)d_in[0];
  const int*   w     = (const int*)d_in[1];
  const float* scale = (const float*)d_in[2];
  const float* zero  = (const float*)d_in[3];
  const float* bias  = (const float*)d_in[4];
  float* out = (float*)d_out;

  const size_t n_x = (size_t)M_DIM * K_DIM;
  const size_t n_w = (size_t)N_DIM * K_DIM;
  const size_t need = n_x * 2 + n_w + (size_t)M_DIM * 8;  // ~112 MB

  if (ws_size < need) {
    dim3 gr(N_DIM / 16, M_DIM / 16);
    fallback_kernel<<<gr, 256, 0, stream>>>(x, w, scale, zero, bias, out);
    return;
  }

  int8_t* x_h = (int8_t*)d_ws;
  int8_t* x_l = x_h + n_x;
  int8_t* w_q = x_l + n_x;
  float* rsum = (float*)(w_q + n_w);
  float* xs   = rsum + M_DIM;

  convert_w_kernel<<<N_DIM / 16, 256, 0, stream>>>(w, w_q);
  quantx_kernel<<<M_DIM, 256, 0, stream>>>(x, x_h, x_l, xs, rsum);

  (void)hipFuncSetAttribute((const void*)qgemm_kernel,
                            hipFuncAttributeMaxDynamicSharedMemorySize, 2 * BUFB);

  const int nblocks = (M_DIM / 128) * (N_DIM / 256);  // 64 * 43 = 2752
  qgemm_kernel<<<nblocks, 512, 2 * BUFB, stream>>>(x_h, x_l, w_q, xs, rsum,
                                                   scale, zero, bias, out);
}